// Round 1
// 344.635 us; speedup vs baseline: 1.0084x; 1.0084x over previous
//
#include <hip/hip_runtime.h>
#include <hip/hip_bf16.h>

#define NB 8
#define C 256
#define LL 6400
#define HEADS 8
#define HC 32
#define NH 64      // NB*HEADS
#define SEG 40     // ctx l-segments
#define SL 160     // LL / SEG
#define ATP 40     // proj At pitch (u16), 80B rows -> 16B-aligned b128 frags
#define QPP 264    // out Q-panel pitch (u16)

typedef unsigned short u16;
typedef unsigned int u32;
typedef __attribute__((ext_vector_type(8))) short bf16x8;
typedef __attribute__((ext_vector_type(4))) float f32x4;

typedef __attribute__((address_space(1))) const u32 ga_u32;
typedef __attribute__((address_space(3))) u32 ls_u32;

__device__ __forceinline__ void gload_lds16(const u16* g, u16* l) {
  __builtin_amdgcn_global_load_lds((ga_u32*)g, (ls_u32*)l, 16, 0, 0);
}

__device__ __forceinline__ float bf2f(u32 u) { return __uint_as_float(u << 16); }
__device__ __forceinline__ u16 f2bf(float f) {
  __hip_bfloat16 h = __float2bfloat16(f);
  return *(u16*)&h;
}
__device__ __forceinline__ void unpack8(uint4 u, float* f) {
  f[0] = bf2f(u.x & 0xffffu); f[1] = bf2f(u.x >> 16);
  f[2] = bf2f(u.y & 0xffffu); f[3] = bf2f(u.y >> 16);
  f[4] = bf2f(u.z & 0xffffu); f[5] = bf2f(u.z >> 16);
  f[6] = bf2f(u.w & 0xffffu); f[7] = bf2f(u.w >> 16);
}

struct WcvtArgs { const float* W[3]; u16* Wb[3]; };
struct PFArgs { const float* X[3]; const u16* Wb[3]; const float* bias[3]; u16* P[3]; };

// ---------------- W fp32 -> bf16 (3 weights, one launch) ----------------
__global__ __launch_bounds__(256) void wcvt(WcvtArgs a) {
  const int idx = blockIdx.x * 256 + threadIdx.x;  // < 3*16384 float4-units
  const int which = idx >> 14, off = (idx & 16383) * 4;
  float4 v = *(const float4*)&a.W[which][off];
  ushort4 o = {f2bf(v.x), f2bf(v.y), f2bf(v.z), f2bf(v.w)};
  *(ushort4*)&a.Wb[which][off] = o;
}

// ------- proj (x3, transpose fused): Pt[l][co] = sum_c X[c][l]*W[co][c] + b -------
// Block: 128 l x 256 co, k-loop BK=32. Double-buffered LDS, ONE raw s_barrier per
// k-step with counted vmcnt(4): the 4 X-prefetch loads (issued a full iteration
// ahead of their consumer) stay in flight across the barrier; only the 4 B
// global_load_lds are drained. Removes the per-k-step HBM-latency stall that had
// all pipes <8% busy (occupancy is hard-capped at 2 waves/SIMD by 128 acc AGPRs,
// so ILP, not TLP, is the only lever).
__global__ __launch_bounds__(256, 2) void proj_fused(PFArgs args) {
  __shared__ __align__(16) u16 At[2][128 * ATP];  // [l][k] transposed X tile
  __shared__ __align__(16) u16 Bs[2][256 * 32];   // [co][k] W (bf16)
  const int which = blockIdx.y >> 3, n = blockIdx.y & 7;
  const int l0 = blockIdx.x * 128;
  const int t = threadIdx.x;
  const int lane = t & 63, wave = t >> 6;
  const int fr = lane & 15, q = lane >> 4;
  const int wl = (wave >> 1) * 64, wco = (wave & 1) * 128;
  const int s32 = t & 31, rcg = t >> 5;        // A staging coords
  const int srow = t >> 2, scol = (t & 3) * 8; // B staging coords
  const float* X = args.X[which] + (size_t)n * C * LL;
  const u16* Wb = args.Wb[which];
  f32x4 acc[4][8] = {};
  float4 xv[4];

  // ---- prologue: stage tile 0 into buf 0, prefetch xv for tile 1 ----
#pragma unroll
  for (int j = 0; j < 4; ++j)
    xv[j] = *(const float4*)&X[(size_t)(rcg * 4 + j) * LL + l0 + s32 * 4];
#pragma unroll
  for (int s = 0; s < 4; ++s)
    gload_lds16(&Wb[(size_t)(s * 64 + srow) * C + scol], &Bs[0][s * 2048 + wave * 512]);
  {
    const float* xf = (const float*)xv;
#pragma unroll
    for (int li = 0; li < 4; ++li) {
      const int lp = li ^ (s32 & 3);  // permuted write order for LDS bank spread
      u32 lo = (u32)f2bf(xf[0 * 4 + lp]) | ((u32)f2bf(xf[1 * 4 + lp]) << 16);
      u32 hi = (u32)f2bf(xf[2 * 4 + lp]) | ((u32)f2bf(xf[3 * 4 + lp]) << 16);
      u32* dst = (u32*)&At[0][(s32 * 4 + lp) * ATP + rcg * 4];
      dst[0] = lo; dst[1] = hi;
    }
  }
  __builtin_amdgcn_sched_barrier(0);
#pragma unroll
  for (int j = 0; j < 4; ++j)
    xv[j] = *(const float4*)&X[(size_t)(32 + rcg * 4 + j) * LL + l0 + s32 * 4];
  asm volatile("s_waitcnt vmcnt(4) lgkmcnt(0)" ::: "memory");  // B(0) done, xv(1) in flight
  __builtin_amdgcn_s_barrier();
  __builtin_amdgcn_sched_barrier(0);

  // ---- main loop: 8 k-steps, single barrier each ----
#pragma unroll
  for (int kt = 0; kt < 8; ++kt) {
    u16* Atc = At[kt & 1];
    u16* Bsc = Bs[kt & 1];
    if (kt < 7) {
      u16* Atn = At[(kt & 1) ^ 1];
      u16* Bsn = Bs[(kt & 1) ^ 1];
      // B tile (kt+1) -> other buffer (L2-resident, drained at this iter's barrier)
#pragma unroll
      for (int s = 0; s < 4; ++s)
        gload_lds16(&Wb[(size_t)(s * 64 + srow) * C + (kt + 1) * 32 + scol],
                    &Bsn[s * 2048 + wave * 512]);
      // A transpose-write (kt+1) from xv regs (loaded one full iteration ago)
      const float* xf = (const float*)xv;
#pragma unroll
      for (int li = 0; li < 4; ++li) {
        const int lp = li ^ (s32 & 3);
        u32 lo = (u32)f2bf(xf[0 * 4 + lp]) | ((u32)f2bf(xf[1 * 4 + lp]) << 16);
        u32 hi = (u32)f2bf(xf[2 * 4 + lp]) | ((u32)f2bf(xf[3 * 4 + lp]) << 16);
        u32* dst = (u32*)&Atn[(s32 * 4 + lp) * ATP + rcg * 4];
        dst[0] = lo; dst[1] = hi;
      }
      __builtin_amdgcn_sched_barrier(0);  // keep xv reissue below the reads above
      if (kt < 6) {
        // xv prefetch for tile kt+2 — stays in flight across the barrier
#pragma unroll
        for (int j = 0; j < 4; ++j)
          xv[j] = *(const float4*)&X[(size_t)((kt + 2) * 32 + rcg * 4 + j) * LL + l0 + s32 * 4];
      }
    }
    // compute current buffer
    bf16x8 a[4];
#pragma unroll
    for (int i = 0; i < 4; ++i)
      a[i] = *(const bf16x8*)&Atc[(wl + i * 16 + fr) * ATP + q * 8];
#pragma unroll
    for (int j = 0; j < 8; ++j) {
      bf16x8 b = *(const bf16x8*)&Bsc[(wco + j * 16 + fr) * 32 + q * 8];
#pragma unroll
      for (int i = 0; i < 4; ++i)
        acc[i][j] = __builtin_amdgcn_mfma_f32_16x16x32_bf16(a[i], b, acc[i][j], 0, 0, 0);
    }
    if (kt < 6) {
      asm volatile("s_waitcnt vmcnt(4) lgkmcnt(0)" ::: "memory");  // B done, xv flying
      __builtin_amdgcn_s_barrier();
      __builtin_amdgcn_sched_barrier(0);
    } else if (kt == 6) {
      asm volatile("s_waitcnt vmcnt(0) lgkmcnt(0)" ::: "memory");  // no xv outstanding
      __builtin_amdgcn_s_barrier();
      __builtin_amdgcn_sched_barrier(0);
    }
  }

  const float* bias = args.bias[which];
  u16* P = args.P[which] + (size_t)n * LL * C;
  float bb[8];
#pragma unroll
  for (int j = 0; j < 8; ++j) bb[j] = bias[wco + j * 16 + fr];
#pragma unroll
  for (int i = 0; i < 4; ++i)
#pragma unroll
    for (int r = 0; r < 4; ++r) {
      const int lrow = l0 + wl + i * 16 + q * 4 + r;
#pragma unroll
      for (int j = 0; j < 8; ++j)
        P[(size_t)lrow * C + wco + j * 16 + fr] = f2bf(acc[i][j][r] + bb[j]);
    }
}

// -------- ctx partials (one pass, no-max softmax): pctx += exp(K)[l,k]*V[l,v] --------
// grid (SEG, NB). Full 512B-row async staging; wave handles 2 heads.
__global__ __launch_bounds__(256) void ctx_part(const u16* __restrict__ Kt,
    const u16* __restrict__ Vt, float* __restrict__ pctx, float* __restrict__ psum) {
  __shared__ __align__(16) u16 Ks[16 * 256];
  __shared__ __align__(16) u16 Vs[16 * 256];
  const int seg = blockIdx.x, n = blockIdx.y;
  const int t = threadIdx.x, lane = t & 63, wave = t >> 6;
  const int l0 = seg * SL;
  const u16* KtN = Kt + (size_t)n * LL * C;
  const u16* VtN = Vt + (size_t)n * LL * C;
  const int k4 = (lane & 7) * 4, v8 = lane >> 3;
  float acc[2][4][4] = {};
  float ssum[2][4] = {};
  for (int ls = 0; ls < SL; ls += 16) {
    __syncthreads();
#pragma unroll
    for (int i = 0; i < 2; ++i) {
      const int r = wave * 4 + i * 2;
      gload_lds16(&KtN[(size_t)(l0 + ls + r) * C + lane * 8], &Ks[r * 256]);
      gload_lds16(&VtN[(size_t)(l0 + ls + r) * C + lane * 8], &Vs[r * 256]);
    }
    __syncthreads();
#pragma unroll
    for (int hh = 0; hh < 2; ++hh) {
      const int h = wave * 2 + hh;
#pragma unroll
      for (int l = 0; l < 16; ++l) {
        ushort4 ku = *(const ushort4*)&Ks[l * 256 + h * 32 + k4];
        ushort4 vu = *(const ushort4*)&Vs[l * 256 + h * 32 + v8 * 4];
        float ek[4] = {__expf(bf2f(ku.x)), __expf(bf2f(ku.y)),
                       __expf(bf2f(ku.z)), __expf(bf2f(ku.w))};
        float vf[4] = {bf2f(vu.x), bf2f(vu.y), bf2f(vu.z), bf2f(vu.w)};
#pragma unroll
        for (int i = 0; i < 4; ++i)
#pragma unroll
          for (int j = 0; j < 4; ++j) acc[hh][i][j] = fmaf(ek[i], vf[j], acc[hh][i][j]);
        if (v8 == 0)
#pragma unroll
          for (int i = 0; i < 4; ++i) ssum[hh][i] += ek[i];
      }
    }
  }
#pragma unroll
  for (int hh = 0; hh < 2; ++hh) {
    const int h = wave * 2 + hh;
    const size_t pb = ((size_t)seg * NH + n * 8 + h) * 1024;
#pragma unroll
    for (int i = 0; i < 4; ++i)
#pragma unroll
      for (int j = 0; j < 4; ++j)
        pctx[pb + (size_t)(k4 + i) * 32 + v8 * 4 + j] = acc[hh][i][j];
    if (v8 == 0) {
      const size_t sb = ((size_t)seg * NH + n * 8 + h) * 32;
#pragma unroll
      for (int i = 0; i < 4; ++i) psum[sb + k4 + i] = ssum[hh][i];
    }
  }
}

// ---------------- reduce partials + normalize: ctx = (sum pctx) / (sum psum) ----------------
__global__ __launch_bounds__(256) void ctx_reduce(const float* __restrict__ pctx,
    const float* __restrict__ psum, float* __restrict__ ctx) {
  const int idx = blockIdx.x * 256 + threadIdx.x;  // < NH*1024
  const int nh = idx >> 10, e = idx & 1023, k = e >> 5;
  float s = 0.f, ss = 0.f;
  for (int g = 0; g < SEG; ++g) {
    s += pctx[(size_t)(g * NH + nh) * 1024 + e];
    ss += psum[(size_t)(g * NH + nh) * 32 + k];
  }
  ctx[idx] = s / ss;
}

// ---------------- fuse: M_n[o, h*32+k] = sum_v Wr[o,h*32+v]*ctx[n,h,k,v], bf16 ----------------
__global__ __launch_bounds__(256) void mfuse(const float* __restrict__ Wr,
    const float* __restrict__ ctx, u16* __restrict__ M) {
  const int idx = blockIdx.x * 256 + threadIdx.x;  // < NB*C*C
  const int hk = idx & 255;
  const int o = (idx >> 8) & 255;
  const int n = idx >> 16;
  const int h = hk >> 5, k = hk & 31;
  const float* wr = Wr + (size_t)o * C + h * HC;
  const float* cx = ctx + ((size_t)(n * HEADS + h) * HC + k) * HC;
  float s = 0.f;
#pragma unroll
  for (int v = 0; v < HC; ++v) s = fmaf(wr[v], cx[v], s);
  M[idx] = f2bf(s);
}

// ---- out[co][l] = sum_k M[co][k]*softmaxQ[l][k] + br[co] + Xq[co][l], fp32 ----
// Block: 64 l x 256 co. Q staged+softmaxed ONCE into persistent LDS panel;
// M tile double-buffered, single raw barrier per k-step (16 barriers vs 32),
// M staging overlapped under the MFMA phase.
__global__ __launch_bounds__(256) void out_fused(const u16* __restrict__ Qt,
    const u16* __restrict__ Mb, const float* __restrict__ br,
    const float* __restrict__ Xq, float* __restrict__ out) {
  __shared__ __align__(16) u16 Qp[64 * QPP];     // softmaxed Q, [l][k]
  __shared__ __align__(16) u16 As[2][128 * 32];  // M tile [co][k], double-buffered
  const int n = blockIdx.y, l0 = blockIdx.x * 64;
  const int t = threadIdx.x, lane = t & 63, wave = t >> 6;
  const int fr = lane & 15, q = lane >> 4;
  const int wcoL = (wave >> 1) * 64, wl = (wave & 1) * 32;
  const int srow = t >> 2, scol = (t & 3) * 8;
  const u16* QtN = Qt + (size_t)n * LL * C;
  const u16* MbN = Mb + (size_t)n * C * C;

  // issue first M-tile stage early so it hides under the Q softmax phase
#pragma unroll
  for (int s = 0; s < 2; ++s)
    gload_lds16(&MbN[(size_t)(s * 64 + srow) * C + scol], &As[0][s * 2048 + wave * 512]);

#pragma unroll
  for (int p = 0; p < 2; ++p) {
    const int row = p * 32 + (t >> 3);
    const int g = t & 7;
    const uint4* src = (const uint4*)&QtN[(size_t)(l0 + row) * C + g * 32];
    uint4 u0 = src[0], u1 = src[1], u2 = src[2], u3 = src[3];
    float v[32];
    unpack8(u0, v); unpack8(u1, v + 8); unpack8(u2, v + 16); unpack8(u3, v + 24);
    float e[32], s = 0.f;
#pragma unroll
    for (int j = 0; j < 32; ++j) { e[j] = __expf(v[j]); s += e[j]; }
    const float r = 1.0f / s;
    uint4* drow = (uint4*)&Qp[row * QPP + g * 32];
#pragma unroll
    for (int b4 = 0; b4 < 4; ++b4) {
      union { uint4 u; u16 h[8]; } o;
#pragma unroll
      for (int j = 0; j < 8; ++j) o.h[j] = f2bf(e[b4 * 8 + j] * r);
      drow[b4] = o.u;
    }
  }
  asm volatile("s_waitcnt vmcnt(0) lgkmcnt(0)" ::: "memory");
  __builtin_amdgcn_s_barrier();
  __builtin_amdgcn_sched_barrier(0);

  f32x4 acc[2][4][2] = {};
#pragma unroll
  for (int it = 0; it < 16; ++it) {
    const int coh = it >> 3, k0 = (it & 7) * 32, cur = it & 1;
    if (it < 15) {
      const int nco = (it + 1) >> 3, nk0 = ((it + 1) & 7) * 32;
#pragma unroll
      for (int s = 0; s < 2; ++s)
        gload_lds16(&MbN[(size_t)(nco * 128 + s * 64 + srow) * C + nk0 + scol],
                    &As[cur ^ 1][s * 2048 + wave * 512]);
      __builtin_amdgcn_sched_barrier(0);
    }
    bf16x8 a[4], b[2];
#pragma unroll
    for (int i = 0; i < 4; ++i)
      a[i] = *(const bf16x8*)&As[cur][(wcoL + i * 16 + fr) * 32 + q * 8];
#pragma unroll
    for (int j = 0; j < 2; ++j)
      b[j] = *(const bf16x8*)&Qp[(wl + j * 16 + fr) * QPP + k0 + q * 8];
#pragma unroll
    for (int i = 0; i < 4; ++i)
#pragma unroll
      for (int j = 0; j < 2; ++j)
        acc[coh][i][j] = __builtin_amdgcn_mfma_f32_16x16x32_bf16(a[i], b[j], acc[coh][i][j], 0, 0, 0);
    if (it < 15) {
      asm volatile("s_waitcnt vmcnt(0) lgkmcnt(0)" ::: "memory");
      __builtin_amdgcn_s_barrier();
      __builtin_amdgcn_sched_barrier(0);
    }
  }

  const float* XqN = Xq + (size_t)n * C * LL;
  float* On = out + (size_t)n * C * LL;
#pragma unroll
  for (int coh = 0; coh < 2; ++coh)
#pragma unroll
    for (int i = 0; i < 4; ++i)
#pragma unroll
      for (int r = 0; r < 4; ++r) {
        const int co = coh * 128 + wcoL + i * 16 + q * 4 + r;
        const float bb = br[co];
#pragma unroll
        for (int j = 0; j < 2; ++j) {
          const int l = l0 + wl + j * 16 + fr;
          const size_t off = (size_t)co * LL + l;
          On[off] = acc[coh][i][j][r] + bb + XqN[off];
        }
      }
}

extern "C" void kernel_launch(void* const* d_in, const int* in_sizes, int n_in,
                              void* d_out, int out_size, void* d_ws, size_t ws_size,
                              hipStream_t stream) {
  const float* Xq = (const float*)d_in[0];
  const float* Xk = (const float*)d_in[1];
  const float* Xv = (const float*)d_in[2];
  const float* Wq = (const float*)d_in[3];
  const float* bq = (const float*)d_in[4];
  const float* Wk = (const float*)d_in[5];
  const float* bk = (const float*)d_in[6];
  const float* Wv = (const float*)d_in[7];
  const float* bv = (const float*)d_in[8];
  const float* Wr = (const float*)d_in[9];
  const float* br = (const float*)d_in[10];
  float* out = (float*)d_out;

  char* ws = (char*)d_ws;
  const size_t nelem = (size_t)NB * LL * C;  // per [L][C] bf16 buffer
  u16* Qt = (u16*)ws;
  u16* Kt = (u16*)(ws + nelem * 2);
  u16* Vt = (u16*)(ws + nelem * 4);
  char* p = ws + nelem * 6;
  u16* Wqb = (u16*)p; p += C * C * 2;
  u16* Wkb = (u16*)p; p += C * C * 2;
  u16* Wvb = (u16*)p; p += C * C * 2;
  float* pctx = (float*)p; p += (size_t)SEG * NH * HC * HC * 4;
  float* psum = (float*)p; p += (size_t)SEG * NH * HC * 4;
  float* ctx = (float*)p;  p += (size_t)NH * HC * HC * 4;
  u16* Mb = (u16*)p;

  WcvtArgs wa;
  wa.W[0] = Wq; wa.W[1] = Wk; wa.W[2] = Wv;
  wa.Wb[0] = Wqb; wa.Wb[1] = Wkb; wa.Wb[2] = Wvb;
  wcvt<<<192, 256, 0, stream>>>(wa);

  PFArgs pa;
  pa.X[0] = Xq; pa.X[1] = Xk; pa.X[2] = Xv;
  pa.Wb[0] = Wqb; pa.Wb[1] = Wkb; pa.Wb[2] = Wvb;
  pa.bias[0] = bq; pa.bias[1] = bk; pa.bias[2] = bv;
  pa.P[0] = Qt; pa.P[1] = Kt; pa.P[2] = Vt;
  proj_fused<<<dim3(50, 24), 256, 0, stream>>>(pa);

  ctx_part<<<dim3(SEG, NB), 256, 0, stream>>>(Kt, Vt, pctx, psum);
  ctx_reduce<<<NH * HC * HC / 256, 256, 0, stream>>>(pctx, psum, ctx);
  mfuse<<<NB * C * C / 256, 256, 0, stream>>>(Wr, ctx, Mb);
  out_fused<<<dim3(100, NB), 256, 0, stream>>>(Qt, Mb, br, Xq, out);
}

// Round 2
// 321.205 us; speedup vs baseline: 1.0819x; 1.0729x over previous
//
#include <hip/hip_runtime.h>
#include <hip/hip_bf16.h>

#define NB 8
#define C 256
#define LL 6400
#define HEADS 8
#define HC 32
#define NH 64      // NB*HEADS
#define SEG 40     // ctx l-segments
#define SL 160     // LL / SEG
#define ATP 40     // proj At pitch (u16), 80B rows -> 16B-aligned b128 frags
#define QPP 264    // out Q-panel pitch (u16)
#define TPP 272    // proj epilogue transpose pitch (u16): 17x16B rows, bank-clean

typedef unsigned short u16;
typedef unsigned int u32;
typedef __attribute__((ext_vector_type(8))) short bf16x8;
typedef __attribute__((ext_vector_type(4))) float f32x4;

typedef __attribute__((address_space(1))) const u32 ga_u32;
typedef __attribute__((address_space(3))) u32 ls_u32;

__device__ __forceinline__ void gload_lds16(const u16* g, u16* l) {
  __builtin_amdgcn_global_load_lds((ga_u32*)g, (ls_u32*)l, 16, 0, 0);
}

__device__ __forceinline__ float bf2f(u32 u) { return __uint_as_float(u << 16); }
__device__ __forceinline__ u16 f2bf(float f) {
  __hip_bfloat16 h = __float2bfloat16(f);
  return *(u16*)&h;
}
__device__ __forceinline__ void unpack8(uint4 u, float* f) {
  f[0] = bf2f(u.x & 0xffffu); f[1] = bf2f(u.x >> 16);
  f[2] = bf2f(u.y & 0xffffu); f[3] = bf2f(u.y >> 16);
  f[4] = bf2f(u.z & 0xffffu); f[5] = bf2f(u.z >> 16);
  f[6] = bf2f(u.w & 0xffffu); f[7] = bf2f(u.w >> 16);
}

struct WcvtArgs { const float* W[3]; u16* Wb[3]; };
struct PFArgs { const float* X[3]; const u16* Wb[3]; const float* bias[3]; u16* P[3]; };

// ---------------- W fp32 -> bf16 (3 weights, one launch) ----------------
__global__ __launch_bounds__(256) void wcvt(WcvtArgs a) {
  const int idx = blockIdx.x * 256 + threadIdx.x;  // < 3*16384 float4-units
  const int which = idx >> 14, off = (idx & 16383) * 4;
  float4 v = *(const float4*)&a.W[which][off];
  ushort4 o = {f2bf(v.x), f2bf(v.y), f2bf(v.z), f2bf(v.w)};
  *(ushort4*)&a.Wb[which][off] = o;
}

// ------- proj (x3, transpose fused): Pt[l][co] = sum_c X[c][l]*W[co][c] + b -------
// Block: 128 l x 256 co, k-loop BK=32, double-buffered, one s_barrier/k-step,
// counted vmcnt(4) (xv prefetch stays in flight across the barrier).
// CRITICAL (rule #20): the transpose pack is fully STATICALLY indexed. The old
// `lp = li ^ (s32&3)` per-lane runtime index demoted xv[] to scratch (per-lane
// dynamic index can't use movrel), putting a scratch round-trip on the critical
// path each k-step AND polluting vmcnt so the counted-wait pipeline never
// engaged. Bank-conflict cost of static order is negligible (measured 0.006%).
// Epilogue: LDS transpose -> global_store_dwordx4 (full 512B rows), fixing the
// 1.8x write RMW amplification (141 MB vs 78.6 MB ideal).
__global__ __launch_bounds__(256, 2) void proj_fused(PFArgs args) {
  // pool layout: [At0 128*ATP][At1 128*ATP][Bs0 256*32][Bs1 256*32] = 26624 u16
  // epilogue reuses whole pool as [128][TPP] u16 transpose tile = 34816 u16
  __shared__ __align__(16) u16 pool[128 * TPP];
  u16* const Atb[2] = {pool, pool + 128 * ATP};
  u16* const Bsb[2] = {pool + 2 * 128 * ATP, pool + 2 * 128 * ATP + 256 * 32};
  const int which = blockIdx.y >> 3, n = blockIdx.y & 7;
  const int l0 = blockIdx.x * 128;
  const int t = threadIdx.x;
  const int lane = t & 63, wave = t >> 6;
  const int fr = lane & 15, q = lane >> 4;
  const int wl = (wave >> 1) * 64, wco = (wave & 1) * 128;
  const int s32 = t & 31, rcg = t >> 5;        // A staging coords
  const int srow = t >> 2, scol = (t & 3) * 8; // B staging coords
  const float* X = args.X[which] + (size_t)n * C * LL;
  const u16* Wb = args.Wb[which];
  f32x4 acc[4][8] = {};
  float4 xv[4];

  // ---- prologue: stage tile 0 into buf 0, prefetch xv for tile 1 ----
#pragma unroll
  for (int j = 0; j < 4; ++j)
    xv[j] = *(const float4*)&X[(size_t)(rcg * 4 + j) * LL + l0 + s32 * 4];
#pragma unroll
  for (int s = 0; s < 4; ++s)
    gload_lds16(&Wb[(size_t)(s * 64 + srow) * C + scol], &Bsb[0][s * 2048 + wave * 512]);
  {
    const float* xf = (const float*)xv;
#pragma unroll
    for (int li = 0; li < 4; ++li) {  // li STATIC -> xv stays in VGPRs
      u32 lo = (u32)f2bf(xf[0 * 4 + li]) | ((u32)f2bf(xf[1 * 4 + li]) << 16);
      u32 hi = (u32)f2bf(xf[2 * 4 + li]) | ((u32)f2bf(xf[3 * 4 + li]) << 16);
      u32* dst = (u32*)&Atb[0][(s32 * 4 + li) * ATP + rcg * 4];
      dst[0] = lo; dst[1] = hi;
    }
  }
  __builtin_amdgcn_sched_barrier(0);
#pragma unroll
  for (int j = 0; j < 4; ++j)
    xv[j] = *(const float4*)&X[(size_t)(32 + rcg * 4 + j) * LL + l0 + s32 * 4];
  asm volatile("s_waitcnt vmcnt(4) lgkmcnt(0)" ::: "memory");  // B(0) done, xv(1) in flight
  __builtin_amdgcn_s_barrier();
  __builtin_amdgcn_sched_barrier(0);

  // ---- main loop: 8 k-steps, single barrier each ----
#pragma unroll
  for (int kt = 0; kt < 8; ++kt) {
    u16* Atc = Atb[kt & 1];
    u16* Bsc = Bsb[kt & 1];
    if (kt < 7) {
      u16* Atn = Atb[(kt & 1) ^ 1];
      u16* Bsn = Bsb[(kt & 1) ^ 1];
      // B tile (kt+1) -> other buffer (L2-resident, drained at this iter's barrier)
#pragma unroll
      for (int s = 0; s < 4; ++s)
        gload_lds16(&Wb[(size_t)(s * 64 + srow) * C + (kt + 1) * 32 + scol],
                    &Bsn[s * 2048 + wave * 512]);
      // A transpose-write (kt+1) from xv regs (loaded one full iteration ago)
      const float* xf = (const float*)xv;
#pragma unroll
      for (int li = 0; li < 4; ++li) {  // STATIC index
        u32 lo = (u32)f2bf(xf[0 * 4 + li]) | ((u32)f2bf(xf[1 * 4 + li]) << 16);
        u32 hi = (u32)f2bf(xf[2 * 4 + li]) | ((u32)f2bf(xf[3 * 4 + li]) << 16);
        u32* dst = (u32*)&Atn[(s32 * 4 + li) * ATP + rcg * 4];
        dst[0] = lo; dst[1] = hi;
      }
      __builtin_amdgcn_sched_barrier(0);  // keep xv reissue below the reads above
      if (kt < 6) {
        // xv prefetch for tile kt+2 — stays in flight across the barrier
#pragma unroll
        for (int j = 0; j < 4; ++j)
          xv[j] = *(const float4*)&X[(size_t)((kt + 2) * 32 + rcg * 4 + j) * LL + l0 + s32 * 4];
      }
    }
    // compute current buffer
    bf16x8 a[4];
#pragma unroll
    for (int i = 0; i < 4; ++i)
      a[i] = *(const bf16x8*)&Atc[(wl + i * 16 + fr) * ATP + q * 8];
#pragma unroll
    for (int j = 0; j < 8; ++j) {
      bf16x8 b = *(const bf16x8*)&Bsc[(wco + j * 16 + fr) * 32 + q * 8];
#pragma unroll
      for (int i = 0; i < 4; ++i)
        acc[i][j] = __builtin_amdgcn_mfma_f32_16x16x32_bf16(a[i], b, acc[i][j], 0, 0, 0);
    }
    if (kt < 6) {
      asm volatile("s_waitcnt vmcnt(4) lgkmcnt(0)" ::: "memory");  // B done, xv flying
      __builtin_amdgcn_s_barrier();
      __builtin_amdgcn_sched_barrier(0);
    } else if (kt == 6) {
      asm volatile("s_waitcnt vmcnt(0) lgkmcnt(0)" ::: "memory");  // no xv outstanding
      __builtin_amdgcn_s_barrier();
      __builtin_amdgcn_sched_barrier(0);
    }
  }

  // ---- epilogue: bias + bf16 -> LDS transpose -> coalesced 512B-row stores ----
  const float* bias = args.bias[which];
  u16* P = args.P[which] + (size_t)n * LL * C;
  float bb[8];
#pragma unroll
  for (int j = 0; j < 8; ++j) bb[j] = bias[wco + j * 16 + fr];
  __syncthreads();  // all waves done reading At/Bs before pool reuse
#pragma unroll
  for (int i = 0; i < 4; ++i)
#pragma unroll
    for (int r = 0; r < 4; ++r) {
      const int lrow = wl + i * 16 + q * 4 + r;  // 0..127 block-local
#pragma unroll
      for (int j = 0; j < 8; ++j)
        pool[lrow * TPP + wco + j * 16 + fr] = f2bf(acc[i][j][r] + bb[j]);
    }
  __syncthreads();
  const int rg = t >> 5, ch = t & 31;  // row group, 16B chunk
#pragma unroll
  for (int s = 0; s < 16; ++s) {
    const int row = rg * 16 + s;
    bf16x8 vrow = *(const bf16x8*)&pool[row * TPP + ch * 8];
    *(bf16x8*)&P[(size_t)(l0 + row) * C + ch * 8] = vrow;  // 512B/row, full lines
  }
}

// -------- ctx partials (one pass, no-max softmax): pctx += exp(K)[l,k]*V[l,v] --------
// grid (SEG, NB). Full 512B-row async staging; wave handles 2 heads.
__global__ __launch_bounds__(256) void ctx_part(const u16* __restrict__ Kt,
    const u16* __restrict__ Vt, float* __restrict__ pctx, float* __restrict__ psum) {
  __shared__ __align__(16) u16 Ks[16 * 256];
  __shared__ __align__(16) u16 Vs[16 * 256];
  const int seg = blockIdx.x, n = blockIdx.y;
  const int t = threadIdx.x, lane = t & 63, wave = t >> 6;
  const int l0 = seg * SL;
  const u16* KtN = Kt + (size_t)n * LL * C;
  const u16* VtN = Vt + (size_t)n * LL * C;
  const int k4 = (lane & 7) * 4, v8 = lane >> 3;
  float acc[2][4][4] = {};
  float ssum[2][4] = {};
  for (int ls = 0; ls < SL; ls += 16) {
    __syncthreads();
#pragma unroll
    for (int i = 0; i < 2; ++i) {
      const int r = wave * 4 + i * 2;
      gload_lds16(&KtN[(size_t)(l0 + ls + r) * C + lane * 8], &Ks[r * 256]);
      gload_lds16(&VtN[(size_t)(l0 + ls + r) * C + lane * 8], &Vs[r * 256]);
    }
    __syncthreads();
#pragma unroll
    for (int hh = 0; hh < 2; ++hh) {
      const int h = wave * 2 + hh;
#pragma unroll
      for (int l = 0; l < 16; ++l) {
        ushort4 ku = *(const ushort4*)&Ks[l * 256 + h * 32 + k4];
        ushort4 vu = *(const ushort4*)&Vs[l * 256 + h * 32 + v8 * 4];
        float ek[4] = {__expf(bf2f(ku.x)), __expf(bf2f(ku.y)),
                       __expf(bf2f(ku.z)), __expf(bf2f(ku.w))};
        float vf[4] = {bf2f(vu.x), bf2f(vu.y), bf2f(vu.z), bf2f(vu.w)};
#pragma unroll
        for (int i = 0; i < 4; ++i)
#pragma unroll
          for (int j = 0; j < 4; ++j) acc[hh][i][j] = fmaf(ek[i], vf[j], acc[hh][i][j]);
        if (v8 == 0)
#pragma unroll
          for (int i = 0; i < 4; ++i) ssum[hh][i] += ek[i];
      }
    }
  }
#pragma unroll
  for (int hh = 0; hh < 2; ++hh) {
    const int h = wave * 2 + hh;
    const size_t pb = ((size_t)seg * NH + n * 8 + h) * 1024;
#pragma unroll
    for (int i = 0; i < 4; ++i)
#pragma unroll
      for (int j = 0; j < 4; ++j)
        pctx[pb + (size_t)(k4 + i) * 32 + v8 * 4 + j] = acc[hh][i][j];
    if (v8 == 0) {
      const size_t sb = ((size_t)seg * NH + n * 8 + h) * 32;
#pragma unroll
      for (int i = 0; i < 4; ++i) psum[sb + k4 + i] = ssum[hh][i];
    }
  }
}

// ---------------- reduce partials + normalize: ctx = (sum pctx) / (sum psum) ----------------
__global__ __launch_bounds__(256) void ctx_reduce(const float* __restrict__ pctx,
    const float* __restrict__ psum, float* __restrict__ ctx) {
  const int idx = blockIdx.x * 256 + threadIdx.x;  // < NH*1024
  const int nh = idx >> 10, e = idx & 1023, k = e >> 5;
  float s = 0.f, ss = 0.f;
  for (int g = 0; g < SEG; ++g) {
    s += pctx[(size_t)(g * NH + nh) * 1024 + e];
    ss += psum[(size_t)(g * NH + nh) * 32 + k];
  }
  ctx[idx] = s / ss;
}

// ---------------- fuse: M_n[o, h*32+k] = sum_v Wr[o,h*32+v]*ctx[n,h,k,v], bf16 ----------------
__global__ __launch_bounds__(256) void mfuse(const float* __restrict__ Wr,
    const float* __restrict__ ctx, u16* __restrict__ M) {
  const int idx = blockIdx.x * 256 + threadIdx.x;  // < NB*C*C
  const int hk = idx & 255;
  const int o = (idx >> 8) & 255;
  const int n = idx >> 16;
  const int h = hk >> 5, k = hk & 31;
  const float* wr = Wr + (size_t)o * C + h * HC;
  const float* cx = ctx + ((size_t)(n * HEADS + h) * HC + k) * HC;
  float s = 0.f;
#pragma unroll
  for (int v = 0; v < HC; ++v) s = fmaf(wr[v], cx[v], s);
  M[idx] = f2bf(s);
}

// ---- out[co][l] = sum_k M[co][k]*softmaxQ[l][k] + br[co] + Xq[co][l], fp32 ----
// Block: 64 l x 256 co. Q staged+softmaxed ONCE into persistent LDS panel;
// M tile double-buffered, single raw barrier per k-step (16 barriers vs 32),
// M staging overlapped under the MFMA phase.
__global__ __launch_bounds__(256) void out_fused(const u16* __restrict__ Qt,
    const u16* __restrict__ Mb, const float* __restrict__ br,
    const float* __restrict__ Xq, float* __restrict__ out) {
  __shared__ __align__(16) u16 Qp[64 * QPP];     // softmaxed Q, [l][k]
  __shared__ __align__(16) u16 As[2][128 * 32];  // M tile [co][k], double-buffered
  const int n = blockIdx.y, l0 = blockIdx.x * 64;
  const int t = threadIdx.x, lane = t & 63, wave = t >> 6;
  const int fr = lane & 15, q = lane >> 4;
  const int wcoL = (wave >> 1) * 64, wl = (wave & 1) * 32;
  const int srow = t >> 2, scol = (t & 3) * 8;
  const u16* QtN = Qt + (size_t)n * LL * C;
  const u16* MbN = Mb + (size_t)n * C * C;

  // issue first M-tile stage early so it hides under the Q softmax phase
#pragma unroll
  for (int s = 0; s < 2; ++s)
    gload_lds16(&MbN[(size_t)(s * 64 + srow) * C + scol], &As[0][s * 2048 + wave * 512]);

#pragma unroll
  for (int p = 0; p < 2; ++p) {
    const int row = p * 32 + (t >> 3);
    const int g = t & 7;
    const uint4* src = (const uint4*)&QtN[(size_t)(l0 + row) * C + g * 32];
    uint4 u0 = src[0], u1 = src[1], u2 = src[2], u3 = src[3];
    float v[32];
    unpack8(u0, v); unpack8(u1, v + 8); unpack8(u2, v + 16); unpack8(u3, v + 24);
    float e[32], s = 0.f;
#pragma unroll
    for (int j = 0; j < 32; ++j) { e[j] = __expf(v[j]); s += e[j]; }
    const float r = 1.0f / s;
    uint4* drow = (uint4*)&Qp[row * QPP + g * 32];
#pragma unroll
    for (int b4 = 0; b4 < 4; ++b4) {
      union { uint4 u; u16 h[8]; } o;
#pragma unroll
      for (int j = 0; j < 8; ++j) o.h[j] = f2bf(e[b4 * 8 + j] * r);
      drow[b4] = o.u;
    }
  }
  asm volatile("s_waitcnt vmcnt(0) lgkmcnt(0)" ::: "memory");
  __builtin_amdgcn_s_barrier();
  __builtin_amdgcn_sched_barrier(0);

  f32x4 acc[2][4][2] = {};
#pragma unroll
  for (int it = 0; it < 16; ++it) {
    const int coh = it >> 3, k0 = (it & 7) * 32, cur = it & 1;
    if (it < 15) {
      const int nco = (it + 1) >> 3, nk0 = ((it + 1) & 7) * 32;
#pragma unroll
      for (int s = 0; s < 2; ++s)
        gload_lds16(&MbN[(size_t)(nco * 128 + s * 64 + srow) * C + nk0 + scol],
                    &As[cur ^ 1][s * 2048 + wave * 512]);
      __builtin_amdgcn_sched_barrier(0);
    }
    bf16x8 a[4], b[2];
#pragma unroll
    for (int i = 0; i < 4; ++i)
      a[i] = *(const bf16x8*)&As[cur][(wcoL + i * 16 + fr) * 32 + q * 8];
#pragma unroll
    for (int j = 0; j < 2; ++j)
      b[j] = *(const bf16x8*)&Qp[(wl + j * 16 + fr) * QPP + k0 + q * 8];
#pragma unroll
    for (int i = 0; i < 4; ++i)
#pragma unroll
      for (int j = 0; j < 2; ++j)
        acc[coh][i][j] = __builtin_amdgcn_mfma_f32_16x16x32_bf16(a[i], b[j], acc[coh][i][j], 0, 0, 0);
    if (it < 15) {
      asm volatile("s_waitcnt vmcnt(0) lgkmcnt(0)" ::: "memory");
      __builtin_amdgcn_s_barrier();
      __builtin_amdgcn_sched_barrier(0);
    }
  }

  const float* XqN = Xq + (size_t)n * C * LL;
  float* On = out + (size_t)n * C * LL;
#pragma unroll
  for (int coh = 0; coh < 2; ++coh)
#pragma unroll
    for (int i = 0; i < 4; ++i)
#pragma unroll
      for (int r = 0; r < 4; ++r) {
        const int co = coh * 128 + wcoL + i * 16 + q * 4 + r;
        const float bb = br[co];
#pragma unroll
        for (int j = 0; j < 2; ++j) {
          const int l = l0 + wl + j * 16 + fr;
          const size_t off = (size_t)co * LL + l;
          On[off] = acc[coh][i][j][r] + bb + XqN[off];
        }
      }
}

extern "C" void kernel_launch(void* const* d_in, const int* in_sizes, int n_in,
                              void* d_out, int out_size, void* d_ws, size_t ws_size,
                              hipStream_t stream) {
  const float* Xq = (const float*)d_in[0];
  const float* Xk = (const float*)d_in[1];
  const float* Xv = (const float*)d_in[2];
  const float* Wq = (const float*)d_in[3];
  const float* bq = (const float*)d_in[4];
  const float* Wk = (const float*)d_in[5];
  const float* bk = (const float*)d_in[6];
  const float* Wv = (const float*)d_in[7];
  const float* bv = (const float*)d_in[8];
  const float* Wr = (const float*)d_in[9];
  const float* br = (const float*)d_in[10];
  float* out = (float*)d_out;

  char* ws = (char*)d_ws;
  const size_t nelem = (size_t)NB * LL * C;  // per [L][C] bf16 buffer
  u16* Qt = (u16*)ws;
  u16* Kt = (u16*)(ws + nelem * 2);
  u16* Vt = (u16*)(ws + nelem * 4);
  char* p = ws + nelem * 6;
  u16* Wqb = (u16*)p; p += C * C * 2;
  u16* Wkb = (u16*)p; p += C * C * 2;
  u16* Wvb = (u16*)p; p += C * C * 2;
  float* pctx = (float*)p; p += (size_t)SEG * NH * HC * HC * 4;
  float* psum = (float*)p; p += (size_t)SEG * NH * HC * 4;
  float* ctx = (float*)p;  p += (size_t)NH * HC * HC * 4;
  u16* Mb = (u16*)p;

  WcvtArgs wa;
  wa.W[0] = Wq; wa.W[1] = Wk; wa.W[2] = Wv;
  wa.Wb[0] = Wqb; wa.Wb[1] = Wkb; wa.Wb[2] = Wvb;
  wcvt<<<192, 256, 0, stream>>>(wa);

  PFArgs pa;
  pa.X[0] = Xq; pa.X[1] = Xk; pa.X[2] = Xv;
  pa.Wb[0] = Wqb; pa.Wb[1] = Wkb; pa.Wb[2] = Wvb;
  pa.bias[0] = bq; pa.bias[1] = bk; pa.bias[2] = bv;
  pa.P[0] = Qt; pa.P[1] = Kt; pa.P[2] = Vt;
  proj_fused<<<dim3(50, 24), 256, 0, stream>>>(pa);

  ctx_part<<<dim3(SEG, NB), 256, 0, stream>>>(Kt, Vt, pctx, psum);
  ctx_reduce<<<NH * HC * HC / 256, 256, 0, stream>>>(pctx, psum, ctx);
  mfuse<<<NB * C * C / 256, 256, 0, stream>>>(Wr, ctx, Mb);
  out_fused<<<dim3(100, NB), 256, 0, stream>>>(Qt, Mb, br, Xq, out);
}